// Round 3
// baseline (211.519 us; speedup 1.0000x reference)
//
#include <hip/hip_runtime.h>

#define BB 8
#define NN 8192
#define SS 2048
#define CC 64
#define NS 32
#define COUT 67   // 3 xyz + 64 feature channels

// ---------------- Kernel A: ball-query scan + xyz channels ----------------
// One wave per query. Unrolled 4x64 = 256 points per latency chain.
// dx/dy/dz are already in registers at hit time, so channels 0..2 of the
// output (grouped_xyz - center) are written here, not in the gather pass.
__global__ __launch_bounds__(256) void scan_kernel(
    const float* __restrict__ xyz,      // (B, N, 3)
    const float* __restrict__ new_xyz,  // (B, S, 3)
    int* __restrict__ idx_ws,           // (B*S, NS)
    float* __restrict__ out)            // (B, 67, S, NS)
{
#pragma clang fp contract(off)
    const int wave = threadIdx.x >> 6;
    const int lane = threadIdx.x & 63;
    const int qid  = blockIdx.x * 4 + wave;
    const int b = qid >> 11;
    const int s = qid & 2047;

    const float R2 = 0.04f;   // f32 nearest of 0.2*0.2; strict '<' matches ref

    const float* ctr = new_xyz + ((size_t)b * SS + s) * 3;
    const float cx = ctr[0], cy = ctr[1], cz = ctr[2];
    const float* xb = xyz + (size_t)b * NN * 3;

    int* myidx = idx_ws + (size_t)qid * NS;
    const unsigned long long lt = (1ull << lane) - 1ull;

    const size_t plane = (size_t)SS * NS;
    float* oxyz = out + (size_t)b * COUT * plane + (size_t)s * NS;

    int total = 0;
    int firstIdx = -1;
    for (int j0 = 0; j0 < NN && total < NS; j0 += 256) {
        float dxv[4], dyv[4], dzv[4];
#pragma unroll
        for (int u = 0; u < 4; ++u) {
            const int j = j0 + u * 64 + lane;
            const float* p = xb + (size_t)j * 3;
            dxv[u] = p[0] - cx;
            dyv[u] = p[1] - cy;
            dzv[u] = p[2] - cz;
        }
#pragma unroll
        for (int u = 0; u < 4; ++u) {
            float d2 = dxv[u] * dxv[u];
            d2 = d2 + dyv[u] * dyv[u];
            d2 = d2 + dzv[u] * dzv[u];   // ((dx^2+dy^2)+dz^2), no fma contraction
            const bool hit = d2 < R2;
            const unsigned long long mask = __ballot(hit);
            if (firstIdx < 0 && mask != 0ull)
                firstIdx = j0 + u * 64 + __builtin_ctzll(mask);
            if (hit) {
                const int pos = total + __popcll(mask & lt);
                if (pos < NS) {
                    myidx[pos] = j0 + u * 64 + lane;
                    oxyz[pos]             = dxv[u];
                    oxyz[plane + pos]     = dyv[u];
                    oxyz[2 * plane + pos] = dzv[u];
                }
            }
            total += __popcll(mask);
        }
    }
    // pad with first hit (or index 0 if no hits), duplicating its xyz values
    if (total < NS && lane >= total && lane < NS) {
        const int fill = (total > 0) ? firstIdx : 0;
        myidx[lane] = fill;
        const float* p = xb + (size_t)fill * 3;   // L1-hot: was just scanned
        oxyz[lane]             = p[0] - cx;
        oxyz[plane + lane]     = p[1] - cy;
        oxyz[2 * plane + lane] = p[2] - cz;
    }
}

// ---------------- Kernel B: feature gather, contiguous-write tiled ----------
// Block = (b, channel-quad, 128-query tile). Writes 16 KB contiguous runs per
// plane (vs 128 B scattered segments before) so stores stream at fill rate.
// Reads: 16 B per (sample, quad) scattered from L2-resident feat (4x line
// over-read, ~540 MB of L2 traffic — cheap at 35 TB/s).
__global__ __launch_bounds__(256) void gather_kernel(
    const float* __restrict__ feat,     // (B, N, C)
    const int* __restrict__ idx_ws,     // (B*S, NS)
    float* __restrict__ out)            // (B, 67, S, NS)
{
    __shared__ int idx_sh[128 * NS];    // 16 KB
    const int t = threadIdx.x;
    const int sTile = blockIdx.x;       // 0..15 (tiles of 128 queries)
    const int cq    = blockIdx.y;       // 0..15 (channel quads)
    const int b     = blockIdx.z;

    const int qbase = (b << 11) + (sTile << 7);
    const int4* src = (const int4*)(idx_ws + (size_t)qbase * NS);
    int4* dst = (int4*)idx_sh;
#pragma unroll
    for (int i = 0; i < 4; ++i)
        dst[t + 256 * i] = src[t + 256 * i];
    __syncthreads();

    const size_t plane = (size_t)SS * NS;
    const int c0 = 3 + cq * 4;
    const float* fb = feat + (size_t)b * NN * CC + cq * 4;
    float* ob = out + ((size_t)b * COUT + c0) * plane + (size_t)(sTile << 7) * NS;

#pragma unroll 4
    for (int i = 0; i < 16; ++i) {
        const int p = t + (i << 8);              // (s,k) pair, s-major
        const int row = idx_sh[p];
        const float4 f = *(const float4*)(fb + (size_t)row * CC);
        float* o = ob + p;
        o[0]         = f.x;
        o[plane]     = f.y;
        o[2 * plane] = f.z;
        o[3 * plane] = f.w;
    }
}

extern "C" void kernel_launch(void* const* d_in, const int* in_sizes, int n_in,
                              void* d_out, int out_size, void* d_ws, size_t ws_size,
                              hipStream_t stream) {
    const float* xyz     = (const float*)d_in[0];
    const float* new_xyz = (const float*)d_in[1];
    const float* feat    = (const float*)d_in[2];
    float* out = (float*)d_out;
    int* idx_ws = (int*)d_ws;   // B*S*NS ints = 2 MB

    scan_kernel<<<dim3((BB * SS) / 4), dim3(256), 0, stream>>>(xyz, new_xyz, idx_ws, out);
    gather_kernel<<<dim3(16, 16, BB), dim3(256), 0, stream>>>(feat, idx_ws, out);
}

// Round 4
// 195.816 us; speedup vs baseline: 1.0802x; 1.0802x over previous
//
#include <hip/hip_runtime.h>

#define BB 8
#define NN 8192
#define SS 2048
#define CC 64
#define NS 32
#define COUT 67   // 3 xyz + 64 feature channels
#define QT 8      // queries per gather block
#define PMAX 35   // planes in half 0 (3 xyz + 32 feat); half 1 has 32

// ---------------- Kernel A: ball-query scan (R2 version, verified) ----------
__global__ __launch_bounds__(256) void scan_kernel(
    const float* __restrict__ xyz,      // (B, N, 3)
    const float* __restrict__ new_xyz,  // (B, S, 3)
    int* __restrict__ idx_ws)           // (B*S, NS)
{
#pragma clang fp contract(off)
    const int wave = threadIdx.x >> 6;
    const int lane = threadIdx.x & 63;
    const int qid  = blockIdx.x * 4 + wave;
    const int b = qid >> 11;
    const int s = qid & 2047;

    const float R2 = 0.04f;   // f32 nearest of 0.2*0.2; strict '<' matches ref

    const float* ctr = new_xyz + ((size_t)b * SS + s) * 3;
    const float cx = ctr[0], cy = ctr[1], cz = ctr[2];
    const float* xb = xyz + (size_t)b * NN * 3;

    int* myidx = idx_ws + (size_t)qid * NS;
    const unsigned long long lt = (1ull << lane) - 1ull;

    int total = 0;
    int firstIdx = -1;
    for (int j0 = 0; j0 < NN && total < NS; j0 += 256) {
        float d2v[4];
#pragma unroll
        for (int u = 0; u < 4; ++u) {
            const int j = j0 + u * 64 + lane;
            const float* p = xb + (size_t)j * 3;
            const float dx = p[0] - cx;
            const float dy = p[1] - cy;
            const float dz = p[2] - cz;
            float d2 = dx * dx;
            d2 = d2 + dy * dy;
            d2 = d2 + dz * dz;       // ((dx^2+dy^2)+dz^2), no fma contraction
            d2v[u] = d2;
        }
#pragma unroll
        for (int u = 0; u < 4; ++u) {
            const bool hit = d2v[u] < R2;
            const unsigned long long mask = __ballot(hit);
            if (firstIdx < 0 && mask != 0ull)
                firstIdx = j0 + u * 64 + __builtin_ctzll(mask);
            if (hit) {
                const int pos = total + __popcll(mask & lt);
                if (pos < NS) myidx[pos] = j0 + u * 64 + lane;
            }
            total += __popcll(mask);
        }
    }
    if (total < NS) {
        const int fill = (total > 0) ? firstIdx : 0;
        if (lane >= total && lane < NS) myidx[lane] = fill;
    }
}

// ---------------- Kernel B: gather, LDS-transposed contiguous writes --------
// Block = 8 queries x half-of-channels. Read: thread t=(q,k) reads its row's
// 128B half-line as 8 sequential float4 (1 L2 miss + 7 L1 hits) -> full line
// utilization like R2. Write: LDS transpose, then wave w stores plane 4i+w as
// one 64-lane float4 instr = 1KB contiguous run (vs R2's scattered 128B).
__global__ __launch_bounds__(256) void gather_kernel(
    const float* __restrict__ xyz,      // (B, N, 3)
    const float* __restrict__ new_xyz,  // (B, S, 3)
    const float* __restrict__ feat,     // (B, N, C)
    const int* __restrict__ idx_ws,     // (B*S, NS)
    float* __restrict__ out)            // (B, 67, S, NS)
{
#pragma clang fp contract(off)
    __shared__ float tile[PMAX * QT * NS];  // 35 * 256 floats = 35 KB
    __shared__ int idx_sh[QT * NS];         // 1 KB

    const int t     = threadIdx.x;          // = q*32 + k
    const int sTile = blockIdx.x;           // 0..255
    const int half  = blockIdx.y;           // 0..1
    const int b     = blockIdx.z;           // 0..7

    const int s0 = sTile * QT;
    const int qbase = (b << 11) + s0;

    idx_sh[t] = idx_ws[(size_t)qbase * NS + t];
    __syncthreads();

    const int q = t >> 5;
    const int row = idx_sh[t];

    // ---- read phase: fill LDS tile [plane][q*32+k] ----
    const float* frow = feat + ((size_t)b * NN + row) * CC + half * 32;
    if (half == 0) {
        const float* ctr = new_xyz + ((size_t)b * SS + s0 + q) * 3;
        const float* p   = xyz + ((size_t)b * NN + row) * 3;
        tile[0 * 256 + t] = p[0] - ctr[0];
        tile[1 * 256 + t] = p[1] - ctr[1];
        tile[2 * 256 + t] = p[2] - ctr[2];
#pragma unroll
        for (int i = 0; i < 8; ++i) {
            const float4 f = *(const float4*)(frow + i * 4);
            tile[(3 + i * 4 + 0) * 256 + t] = f.x;
            tile[(3 + i * 4 + 1) * 256 + t] = f.y;
            tile[(3 + i * 4 + 2) * 256 + t] = f.z;
            tile[(3 + i * 4 + 3) * 256 + t] = f.w;
        }
    } else {
#pragma unroll
        for (int i = 0; i < 8; ++i) {
            const float4 f = *(const float4*)(frow + i * 4);
            tile[(i * 4 + 0) * 256 + t] = f.x;
            tile[(i * 4 + 1) * 256 + t] = f.y;
            tile[(i * 4 + 2) * 256 + t] = f.z;
            tile[(i * 4 + 3) * 256 + t] = f.w;
        }
    }
    __syncthreads();

    // ---- write phase: one 1KB-contiguous wave-store per plane ----
    const int P     = half ? 32 : PMAX;     // planes this block owns
    const int cbase = half ? PMAX : 0;      // global channel base
    const int wv = t >> 6;
    const int ln = t & 63;
    const size_t plane = (size_t)SS * NS;
    float* ob = out + (((size_t)b * COUT + cbase) * SS + s0) * NS;
#pragma unroll
    for (int i = 0; i < 9; ++i) {
        const int p = i * 4 + wv;
        if (p < P) {
            const float4 v = *(const float4*)(tile + p * 256 + ln * 4);
            *(float4*)(ob + (size_t)p * plane + ln * 4) = v;
        }
    }
}

extern "C" void kernel_launch(void* const* d_in, const int* in_sizes, int n_in,
                              void* d_out, int out_size, void* d_ws, size_t ws_size,
                              hipStream_t stream) {
    const float* xyz     = (const float*)d_in[0];
    const float* new_xyz = (const float*)d_in[1];
    const float* feat    = (const float*)d_in[2];
    float* out = (float*)d_out;
    int* idx_ws = (int*)d_ws;   // B*S*NS ints = 2 MB

    scan_kernel<<<dim3((BB * SS) / 4), dim3(256), 0, stream>>>(xyz, new_xyz, idx_ws);
    gather_kernel<<<dim3(SS / QT, 2, BB), dim3(256), 0, stream>>>(xyz, new_xyz, feat, idx_ws, out);
}